// Round 1
// 223.198 us; speedup vs baseline: 1.0667x; 1.0667x over previous
//
#include <hip/hip_runtime.h>

#define NT 16384
#define NH 2048
#define NE 64
#define TOPK 8

#define TB 32                 // tokens per block
#define KSTEPS 64             // 2048 / 32
#define KQ 4                  // K-split ways (= waves per block)
#define KSW (KSTEPS / KQ)     // 16 k-steps per wave

// output layout (floats)
#define LOFF 0
#define WOFF (NT * NE)
#define IOFF (WOFF + NT * TOPK)
#define MOFF (IOFF + NT * TOPK)

typedef __attribute__((ext_vector_type(8))) short short8;
typedef __attribute__((ext_vector_type(4))) float floatx4;

union FragU { uint4 u; short8 s; };

// exact triple split of (a,b) into 3 packed bf16 words (truncation; residual 2^-24)
__device__ __forceinline__ unsigned pack3(float a, float b, unsigned& w1, unsigned& w2) {
    unsigned au = __float_as_uint(a), bu = __float_as_uint(b);
    unsigned ah0 = au & 0xFFFF0000u, bh0 = bu & 0xFFFF0000u;
    float ra = a - __uint_as_float(ah0);
    float rb = b - __uint_as_float(bh0);
    unsigned ar = __float_as_uint(ra), br = __float_as_uint(rb);
    unsigned ah1 = ar & 0xFFFF0000u, bh1 = br & 0xFFFF0000u;
    float sa = ra - __uint_as_float(ah1);
    float sb = rb - __uint_as_float(bh1);
    w1 = bh1 | (ah1 >> 16);
    w2 = (__float_as_uint(sb) & 0xFFFF0000u) | (__float_as_uint(sa) >> 16);
    return bh0 | (ah0 >> 16);
}

// ---------------------------------------------------------------------------
// Kernel 1: convert W_gate [64 x 2048] f32 -> 3 bf16 planes in B-fragment
// order. Record (t, g, p) = 1KB: lane l holds W_split_p[e = g*16 + (l&15)]
// [k = t*32 + (l>>4)*8 .. +7] as 8 bf16. Total 768 KB, L2-resident.
// ---------------------------------------------------------------------------
__global__ __launch_bounds__(64)
void wconv_kernel(const float* __restrict__ Wg, uint4* __restrict__ wsp) {
    const int b = blockIdx.x;            // 0..255
    const int t = b >> 2, g = b & 3;
    const int l = threadIdx.x;
    const int e  = g * 16 + (l & 15);
    const int k0 = t * 32 + (l >> 4) * 8;
    const float* src = Wg + (size_t)e * NH + k0;
    float4 w0 = *(const float4*)src;
    float4 w1 = *(const float4*)(src + 4);
    unsigned u1[4], u2[4];
    uint4 p0;
    p0.x = pack3(w0.x, w0.y, u1[0], u2[0]);
    p0.y = pack3(w0.z, w0.w, u1[1], u2[1]);
    p0.z = pack3(w1.x, w1.y, u1[2], u2[2]);
    p0.w = pack3(w1.z, w1.w, u1[3], u2[3]);
    uint4* dst = wsp + (size_t)((t * 4 + g) * 3) * 64 + l;
    dst[0]   = p0;
    dst[64]  = make_uint4(u1[0], u1[1], u1[2], u1[3]);
    dst[128] = make_uint4(u2[0], u2[1], u2[2], u2[3]);
}

// ---------------------------------------------------------------------------
// Kernel 2: main. 512 blocks x 256 threads (4 waves). Block owns 32 tokens.
// Wave kh computes partial logits over K-range [kh*512, kh*512+512) for all
// 64 experts: A-frags loaded straight from global X (8 contiguous f32/lane,
// pack3 in registers), B-frags from the preconverted table (coalesced 1KB
// records, L2-hot). NO LDS / NO barriers in the K-loop. LDS only for the
// 4-way k-reduction and the logits tile for top-k.
// ---------------------------------------------------------------------------
__global__ __launch_bounds__(256, 2)
void router_kernel(const float* __restrict__ X, const uint4* __restrict__ wsp,
                   const float* __restrict__ bg, float* __restrict__ out) {
    __shared__ __align__(16) float P[KQ][TB][68];   // 34.8 KB partials
    __shared__ __align__(16) float Ls[TB][68];      //  8.7 KB logits

    const int tid = threadIdx.x;
    const int kh  = tid >> 6;            // wave id = K-quarter
    const int l   = tid & 63;
    const int lr  = l & 15, lq = l >> 4;
    const int tbase = blockIdx.x * TB;

    floatx4 acc[2][4];
#pragma unroll
    for (int a = 0; a < 2; a++)
#pragma unroll
        for (int g = 0; g < 4; g++) acc[a][g] = (floatx4)0.0f;

    // A: lane -> (token row, 8 contiguous k)
    const float* xp0 = X + (size_t)(tbase + lr) * NH + kh * (KSW * 32) + lq * 8;
    const float* xp1 = xp0 + (size_t)16 * NH;
    // B: fragment records for this wave's K-range
    const uint4* wp = wsp + (size_t)(kh * KSW) * 12 * 64 + l;

    // initial A preload (issue before the mask-zero stores)
    float4 a0lo = *(const float4*)xp0;
    float4 a0hi = *(const float4*)(xp0 + 4);
    float4 a1lo = *(const float4*)xp1;
    float4 a1hi = *(const float4*)(xp1 + 4);

    // ---- zero this block's mask slab (overlaps with the K-loop's loads) ----
    {
        float4 z = make_float4(0.f, 0.f, 0.f, 0.f);
#pragma unroll
        for (int m = 0; m < 16; m++) {
            int f2  = tid + 256 * m;          // 0..4095 float4s
            int seg = f2 >> 3;                // (e*8+kk) 0..511
            int off = (f2 & 7) << 2;          // 0..28
            *(float4*)(out + MOFF + (size_t)seg * NT + tbase + off) = z;
        }
    }

    // ---- K-loop: no LDS, no barriers ----
#pragma unroll 2
    for (int t = 0; t < KSW; t++) {
        // B-fragment loads first (so waiting on them doesn't drain A prefetch)
        FragU b[4][3];
        const uint4* wt = wp + t * 768;
#pragma unroll
        for (int g = 0; g < 4; g++)
#pragma unroll
            for (int p = 0; p < 3; p++)
                b[g][p].u = wt[(g * 3 + p) * 64];

        // pack current A into 3-plane fragments
        FragU af[2][3];
        {
            unsigned u1[4], u2[4];
            uint4 q;
            q.x = pack3(a0lo.x, a0lo.y, u1[0], u2[0]);
            q.y = pack3(a0lo.z, a0lo.w, u1[1], u2[1]);
            q.z = pack3(a0hi.x, a0hi.y, u1[2], u2[2]);
            q.w = pack3(a0hi.z, a0hi.w, u1[3], u2[3]);
            af[0][0].u = q;
            af[0][1].u = make_uint4(u1[0], u1[1], u1[2], u1[3]);
            af[0][2].u = make_uint4(u2[0], u2[1], u2[2], u2[3]);
            q.x = pack3(a1lo.x, a1lo.y, u1[0], u2[0]);
            q.y = pack3(a1lo.z, a1lo.w, u1[1], u2[1]);
            q.z = pack3(a1hi.x, a1hi.y, u1[2], u2[2]);
            q.w = pack3(a1hi.z, a1hi.w, u1[3], u2[3]);
            af[1][0].u = q;
            af[1][1].u = make_uint4(u1[0], u1[1], u1[2], u1[3]);
            af[1][2].u = make_uint4(u2[0], u2[1], u2[2], u2[3]);
        }

        // prefetch next A chunk (HBM latency hides under the MFMAs)
        if (t + 1 < KSW) {
            const float* nx0 = xp0 + (t + 1) * 32;
            const float* nx1 = xp1 + (t + 1) * 32;
            a0lo = *(const float4*)nx0;
            a0hi = *(const float4*)(nx0 + 4);
            a1lo = *(const float4*)nx1;
            a1hi = *(const float4*)(nx1 + 4);
        }

        // MFMAs: 2 token-tiles x 4 expert-groups x 6 split-products
#pragma unroll
        for (int g = 0; g < 4; g++)
#pragma unroll
            for (int a = 0; a < 2; a++) {
                acc[a][g] = __builtin_amdgcn_mfma_f32_16x16x32_bf16(af[a][0].s, b[g][0].s, acc[a][g], 0, 0, 0);
                acc[a][g] = __builtin_amdgcn_mfma_f32_16x16x32_bf16(af[a][0].s, b[g][1].s, acc[a][g], 0, 0, 0);
                acc[a][g] = __builtin_amdgcn_mfma_f32_16x16x32_bf16(af[a][1].s, b[g][0].s, acc[a][g], 0, 0, 0);
                acc[a][g] = __builtin_amdgcn_mfma_f32_16x16x32_bf16(af[a][1].s, b[g][1].s, acc[a][g], 0, 0, 0);
                acc[a][g] = __builtin_amdgcn_mfma_f32_16x16x32_bf16(af[a][0].s, b[g][2].s, acc[a][g], 0, 0, 0);
                acc[a][g] = __builtin_amdgcn_mfma_f32_16x16x32_bf16(af[a][2].s, b[g][0].s, acc[a][g], 0, 0, 0);
            }
    }

    // ---- dump partials ----
#pragma unroll
    for (int a = 0; a < 2; a++)
#pragma unroll
        for (int g = 0; g < 4; g++)
#pragma unroll
            for (int r = 0; r < 4; r++)
                P[kh][a * 16 + lq * 4 + r][g * 16 + lr] = acc[a][g][r];
    __syncthreads();

    // ---- 4-way reduce + bias -> Ls + coalesced logits write ----
#pragma unroll
    for (int jj = 0; jj < 2; jj++) {
        int f4  = tid + 256 * jj;            // 0..511 float4s
        int tok = f4 >> 4;
        int e4  = (f4 & 15) << 2;
        float4 s0 = *(float4*)&P[0][tok][e4];
        float4 s1 = *(float4*)&P[1][tok][e4];
        float4 s2 = *(float4*)&P[2][tok][e4];
        float4 s3 = *(float4*)&P[3][tok][e4];
        float4 bb = *(const float4*)(bg + e4);
        float4 v;
        v.x = s0.x + s1.x + s2.x + s3.x + bb.x;
        v.y = s0.y + s1.y + s2.y + s3.y + bb.y;
        v.z = s0.z + s1.z + s2.z + s3.z + bb.z;
        v.w = s0.w + s1.w + s2.w + s3.w + bb.w;
        *(float4*)&Ls[tok][e4] = v;
        *(float4*)(out + LOFF + (size_t)tbase * NE + (size_t)f4 * 4) = v;
    }
    __syncthreads();

    // ---- wave-parallel top-8: 8 lanes per token ----
    const int tok = (tid >> 6) * 8 + ((tid & 63) >> 3);
    const int el  = tid & 7;                 // this lane owns experts el*8..el*8+7
    float4 va = *(float4*)&Ls[tok][el * 8];
    float4 vb = *(float4*)&Ls[tok][el * 8 + 4];
    float v[8] = {va.x, va.y, va.z, va.w, vb.x, vb.y, vb.z, vb.w};

    unsigned msk = 0;
    float m0 = 0.f, ssum = 0.f, myv = 0.f;
    int myi = 0;
#pragma unroll
    for (int r = 0; r < 8; r++) {
        float bv = -3.0e38f; int bi = 64;
#pragma unroll
        for (int j = 0; j < 8; j++) {
            bool better = (((msk >> j) & 1u) == 0u) && (v[j] > bv);  // strict >: lowest idx wins
            bv = better ? v[j] : bv;
            bi = better ? (el * 8 + j) : bi;
        }
#pragma unroll
        for (int s2 = 1; s2 < 8; s2 <<= 1) {
            float ov = __shfl_xor(bv, s2);
            int   oi = __shfl_xor(bi, s2);
            bool take = (ov > bv) || (ov == bv && oi < bi);
            bv = take ? ov : bv;
            bi = take ? oi : bi;
        }
        if ((bi >> 3) == el) msk |= (1u << (bi & 7));
        if (r == 0) m0 = bv;
        ssum += __expf(bv - m0);
        if (r == el) { myv = bv; myi = bi; }   // static r vs runtime el -> cndmask
    }
    float w = __expf(myv - m0) / ssum;
    size_t gt = (size_t)(tbase + tok);
    out[WOFF + gt * TOPK + el] = w;
    out[IOFF + gt * TOPK + el] = (float)myi;
    out[MOFF + (size_t)myi * (TOPK * NT) + (size_t)el * NT + gt] = 1.0f;
}

extern "C" void kernel_launch(void* const* d_in, const int* in_sizes, int n_in,
                              void* d_out, int out_size, void* d_ws, size_t ws_size,
                              hipStream_t stream) {
    const float* X  = (const float*)d_in[0];
    const float* Wg = (const float*)d_in[1];
    const float* bg = (const float*)d_in[2];
    float* out = (float*)d_out;
    uint4* wsp = (uint4*)d_ws;   // needs 768 KB

    hipLaunchKernelGGL(wconv_kernel, dim3(KSTEPS * 4), dim3(64), 0, stream, Wg, wsp);
    hipLaunchKernelGGL(router_kernel, dim3(NT / TB), dim3(256), 0, stream,
                       X, (const uint4*)wsp, bg, out);
}